// Round 3
// baseline (190.318 us; speedup 1.0000x reference)
//
#include <hip/hip_runtime.h>
#include <hip/hip_bf16.h>

#define NN 20000
#define NE 160000
#define CPB 8    // workgroup slots per bucket -> 64*8=512 blocks = 2/CU resident

typedef __attribute__((ext_vector_type(8))) short short8;
typedef __attribute__((ext_vector_type(4))) float floatx4;

__device__ __forceinline__ short f2bf(float f) {
    unsigned u = __float_as_uint(f);
    u += 0x7fff + ((u >> 16) & 1);   // RNE
    return (short)(u >> 16);
}
__device__ __forceinline__ float bf2f(unsigned short u) {
    return __uint_as_float(((unsigned)u) << 16);
}

// ---------------- K1: anchor histogram + per-row rank ----------------
__global__ void k_count(const float* __restrict__ pseudo, const int* __restrict__ ei,
                        int* __restrict__ cntp, int* __restrict__ degi,
                        int* __restrict__ anchor, int* __restrict__ rposa) {
    __shared__ int lh[64];
    int tid = threadIdx.x;
    if (tid < 64) lh[tid] = 0;
    __syncthreads();
    int e = blockIdx.x * 256 + tid;
    if (e < NE) {
        float p0 = pseudo[e*3+0], p1 = pseudo[e*3+1], p2 = pseudo[e*3+2];
        int v0 = min(3, max(0, (int)floorf(p0 * 4.f)));
        int v1 = min(3, max(0, (int)floorf(p1 * 4.f)));
        int v2 = min(3, max(0, (int)floorf(p2 * 4.f)));
        int a = v0 + 4*v1 + 16*v2;
        anchor[e] = a;
        atomicAdd(&lh[a], 1);
        rposa[e] = atomicAdd(&degi[ei[e]], 1);   // rank within destination row
    }
    __syncthreads();
    if (tid < 64 && lh[tid]) atomicAdd(&cntp[tid*32], lh[tid]);
}

// ---------------- K2: exclusive scan over 64 bins ----------------
__global__ void k_scan(const int* __restrict__ cntp, int* __restrict__ off) {
    if (threadIdx.x == 0) {
        int acc = 0;
        for (int i = 0; i < 64; i++) { off[i] = acc; acc += cntp[i*32]; }
        off[64] = acc;
    }
}

// ---------------- K2b: exclusive scan of degi[NN] -> rowoff[NN+1] ----------------
__global__ void k_scanN(const int* __restrict__ degi, int* __restrict__ rowoff) {
    __shared__ int ps[256];
    int t = threadIdx.x;
    int b0 = t * 79;                      // 256*79 = 20224 >= 20001
    int s = 0;
    for (int i = 0; i < 79; i++) { int idx = b0 + i; if (idx < NN) s += degi[idx]; }
    ps[t] = s;
    __syncthreads();
    if (t == 0) { int a = 0; for (int i = 0; i < 256; i++) { int v = ps[i]; ps[i] = a; a += v; } }
    __syncthreads();
    int run = ps[t];
    for (int i = 0; i < 79; i++) {
        int idx = b0 + i;
        if (idx <= NN) rowoff[idx] = run;
        if (idx < NN) run += degi[idx];
    }
}

// ---------------- K3: scatter edge ids into anchor buckets ----------------
__global__ void k_scatter(const int* __restrict__ anchor, const int* __restrict__ off,
                          int* __restrict__ curp, int* __restrict__ eidx) {
    __shared__ int lh[64];
    __shared__ int gb[64];
    int tid = threadIdx.x;
    if (tid < 64) lh[tid] = 0;
    __syncthreads();
    int e = blockIdx.x * 256 + tid;
    int a = 0, r = 0;
    if (e < NE) {
        a = anchor[e];
        r = atomicAdd(&lh[a], 1);
    }
    __syncthreads();
    if (tid < 64) gb[tid] = lh[tid] ? atomicAdd(&curp[tid*32], lh[tid]) : 0;
    __syncthreads();
    if (e < NE) eidx[off[a] + gb[a] + r] = e;
}

// ---------------- K3.5: pre-permute W into MFMA B-fragment order ----------------
__global__ void k_wfrag(const float* __restrict__ w, unsigned short* __restrict__ wf) {
    int b = blockIdx.x;
    int b0 = b & 3, b1 = (b >> 2) & 3, b2 = (b >> 4) & 3;
    int wbase = b0 + 5*b1 + 25*b2;
    int n = threadIdx.x & 63;
    for (int k = (threadIdx.x >> 6); k < 512; k += 4) {
        int s = k >> 6, i = k & 63;
        int widx = wbase + (s & 1) + 5*((s >> 1) & 1) + 25*((s >> 2) & 1);
        float val = w[widx*4096 + i*64 + n];
        int t = k >> 5, j = k & 7, g = (k >> 3) & 3;
        int l = g*16 + (n & 15), nt = n >> 4;
        int f = ((nt*16 + t)*64 + l)*8 + j;
        wf[b*32768 + f] = (unsigned short)f2bf(val);
    }
}

// ---------------- K4: main bucketed spline GEMM (no atomics) ----------------
#define LOADSTAGE(P, E_, COL_, PA_, PB_, PC_, A0_, A1_, B0_, B1_)                 \
    {                                                                              \
        int m_ = cnt - (P);                                                        \
        bool valid_ = er < m_;                                                     \
        E_ = eidx[base + (P) + (valid_ ? er : 0)];                                 \
        COL_ = ei[NE + E_];                                                        \
        PA_ = pseudo[E_*3+0]; PB_ = pseudo[E_*3+1]; PC_ = pseudo[E_*3+2];          \
        const float4* xr_ = (const float4*)(x + COL_*64 + g*8);                    \
        A0_ = xr_[0]; A1_ = xr_[1];                                                \
        const float4* xr2_ = (const float4*)(x + COL_*64 + 32 + g*8);              \
        B0_ = xr2_[0]; B1_ = xr2_[1];                                              \
    }

__global__ __launch_bounds__(256)
void k_main(const float* __restrict__ x, const int* __restrict__ ei,
            const float* __restrict__ pseudo, const unsigned short* __restrict__ wfrag_g,
            const int* __restrict__ off, const int* __restrict__ eidx,
            const int* __restrict__ rowoff, const int* __restrict__ rposa,
            unsigned short* __restrict__ msg) {
    __shared__ unsigned short wf[32768];   // 64 KB
    int b = blockIdx.x & 63;
    int slot = blockIdx.x >> 6;            // 0..CPB-1

    {
        const int4* src = (const int4*)(wfrag_g + b*32768);
        int4* dst = (int4*)wf;
        for (int i = threadIdx.x; i < 4096; i += 256) dst[i] = src[i];
    }
    __syncthreads();

    int base = off[b];
    int cnt  = off[b+1] - base;
    int wv = threadIdx.x >> 6;
    int l  = threadIdx.x & 63;
    int er = l & 15;
    int g  = l >> 4;

    const int STRIDE = CPB * 64;
    int p = slot*64 + wv*16;
    if (p >= cnt) return;

    int eC, colC; float paC, pbC, pcC; float4 xa0, xa1, xb0, xb1;
    LOADSTAGE(p, eC, colC, paC, pbC, pcC, xa0, xa1, xb0, xb1);

    for (; p < cnt; p += STRIDE) {
        int pn = p + STRIDE;
        // prefetch next tile's gather chain
        int eN = 0, colN = 0; float paN = 0, pbN = 0, pcN = 0;
        float4 na0, na1, nb0, nb1;
        if (pn < cnt) LOADSTAGE(pn, eN, colN, paN, pbN, pcN, na0, na1, nb0, nb1);

        int m = min(16, cnt - p);
        bool valid = er < m;

        float va = paC * 4.f, vb = pbC * 4.f, vc = pcC * 4.f;
        float f0 = va - floorf(va);
        float f1 = vb - floorf(vb);
        float f2 = vc - floorf(vc);
        float fb[8];
        #pragma unroll
        for (int s = 0; s < 8; s++) {
            float t0 = (s & 1) ? f0 : 1.f - f0;
            float t1 = (s & 2) ? f1 : 1.f - f1;
            float t2 = (s & 4) ? f2 : 1.f - f2;
            fb[s] = valid ? t0 * t1 * t2 : 0.f;
        }

        float xA[8], xB[8];
        xA[0]=xa0.x; xA[1]=xa0.y; xA[2]=xa0.z; xA[3]=xa0.w;
        xA[4]=xa1.x; xA[5]=xa1.y; xA[6]=xa1.z; xA[7]=xa1.w;
        xB[0]=xb0.x; xB[1]=xb0.y; xB[2]=xb0.z; xB[3]=xb0.w;
        xB[4]=xb1.x; xB[5]=xb1.y; xB[6]=xb1.z; xB[7]=xb1.w;

        floatx4 acc[4];
        #pragma unroll
        for (int nt = 0; nt < 4; nt++) acc[nt] = (floatx4){0.f, 0.f, 0.f, 0.f};

        #pragma unroll
        for (int t = 0; t < 16; t++) {
            const int s = t >> 1;
            const float* xf = (t & 1) ? xB : xA;
            short8 afrag;
            #pragma unroll
            for (int j = 0; j < 8; j++) afrag[j] = f2bf(fb[s] * xf[j]);
            #pragma unroll
            for (int nt = 0; nt < 4; nt++) {
                short8 bfrag = *(const short8*)&wf[((nt*16 + t)*64 + l)*8];
                acc[nt] = __builtin_amdgcn_mfma_f32_16x16x32_bf16(afrag, bfrag, acc[nt], 0, 0, 0);
            }
        }

        // store row-grouped bf16 messages: D row = g*4+r (edge), col = nt*16 + (l&15)
        #pragma unroll
        for (int r = 0; r < 4; r++) {
            int mr = g*4 + r;
            if (mr < m) {
                int em = eidx[base + p + mr];
                int rw = ei[em];
                int dst = rowoff[rw] + rposa[em];
                unsigned short* mp = msg + (size_t)dst*64 + (l & 15);
                #pragma unroll
                for (int nt = 0; nt < 4; nt++)
                    mp[nt*16] = (unsigned short)f2bf(acc[nt][r]);
            }
        }

        // rotate pipeline registers
        eC = eN; colC = colN; paC = paN; pbC = pbN; pcC = pcN;
        xa0 = na0; xa1 = na1; xb0 = nb0; xb1 = nb1;
    }
}

// ---------------- K5: out = rowmean(msg) + x@root + bias ----------------
__global__ void k_final2(const float* __restrict__ x, const float* __restrict__ root,
                         const float* __restrict__ bias, const unsigned short* __restrict__ msg,
                         const int* __restrict__ rowoff, float* __restrict__ out) {
    __shared__ float rs[4096];
    for (int i = threadIdx.x; i < 4096; i += 256) rs[i] = root[i];
    __syncthreads();
    int n = blockIdx.x * 4 + (threadIdx.x >> 6);
    int o = threadIdx.x & 63;
    int b0 = rowoff[n], b1 = rowoff[n+1];
    float v = 0.f;
    for (int j = b0; j < b1; j++) v += bf2f(msg[(size_t)j*64 + o]);
    v *= 1.0f / (float)max(b1 - b0, 1);
    v += bias[o];
    const float* xr = x + n*64;
    #pragma unroll 8
    for (int i = 0; i < 64; i++) v += xr[i] * rs[i*64 + o];
    out[n*64 + o] = v;
}

extern "C" void kernel_launch(void* const* d_in, const int* in_sizes, int n_in,
                              void* d_out, int out_size, void* d_ws, size_t ws_size,
                              hipStream_t stream) {
    const float* x      = (const float*)d_in[0];
    const int*   ei     = (const int*)d_in[1];
    const float* pseudo = (const float*)d_in[2];
    const float* weight = (const float*)d_in[3];
    const float* root   = (const float*)d_in[4];
    const float* bias   = (const float*)d_in[5];
    float* out = (float*)d_out;
    char* ws = (char*)d_ws;

    unsigned short* msg    = (unsigned short*)(ws + 0);        // 20,480,000 B
    int*            degi   = (int*)(ws + 20480000);            //     80,000 B
    int*            cntp   = (int*)(ws + 20560000);            //      8,192 B
    int*            curp   = (int*)(ws + 20568192);            //      8,192 B
    int*            off    = (int*)(ws + 20576384);            //        512 B
    int*            rowoff = (int*)(ws + 20576896);            //     80,128 B
    int*            anchor = (int*)(ws + 20657024);            //    640,000 B
    int*            rposa  = (int*)(ws + 21297024);            //    640,000 B
    int*            eidx   = (int*)(ws + 21937024);            //    640,000 B
    unsigned short* wfg    = (unsigned short*)(ws + 22577024); //  4,194,304 B -> total ~26.8 MB

    // zero degi + cntp + curp (contiguous)
    hipMemsetAsync(ws + 20480000, 0, 96384, stream);

    k_count  <<<(NE + 255)/256, 256, 0, stream>>>(pseudo, ei, cntp, degi, anchor, rposa);
    k_scan   <<<1, 64, 0, stream>>>(cntp, off);
    k_scanN  <<<1, 256, 0, stream>>>(degi, rowoff);
    k_scatter<<<(NE + 255)/256, 256, 0, stream>>>(anchor, off, curp, eidx);
    k_wfrag  <<<64, 256, 0, stream>>>(weight, wfg);
    k_main   <<<64*CPB, 256, 0, stream>>>(x, ei, pseudo, wfg, off, eidx, rowoff, rposa, msg);
    k_final2 <<<NN/4, 256, 0, stream>>>(x, root, bias, msg, rowoff, out);
}